// Round 22
// baseline (440.804 us; speedup 1.0000x reference)
//
#include <hip/hip_runtime.h>
#include <math.h>

#define MAX_K 32
#define CUTOFF 5.0f

// Sign map (resolved R1-R6): canonical(max-component-positive) -> LAPACK.
#define SIGN0 -1.0f
#define SIGN1 -1.0f
#define SIGN2 -1.0f

// ---------------- fast path: counting-sort by atom ----------------

// fused: per-edge r + RANK TAGGING (R20 win). One memory-side atomic per
// edge (~23 G/s floor, R6/R21 measured); WRITE_SIZE ~112MB = 3.2M x 32B
// RMW is intrinsic. All streams nt (use-once).
__global__ __launch_bounds__(256) void r_hist_kernel(const float* __restrict__ vec,
                                                     const int* __restrict__ atom,
                                                     float* __restrict__ r_all,
                                                     int* __restrict__ count, int E) {
  int e = blockIdx.x * blockDim.x + threadIdx.x;
  if (e >= E) return;
  float x = __builtin_nontemporal_load(&vec[3 * e + 0]);
  float y = __builtin_nontemporal_load(&vec[3 * e + 1]);
  float z = __builtin_nontemporal_load(&vec[3 * e + 2]);
  float r = sqrtf(x * x + y * y + z * z) * (1.0f / CUTOFF);
  int a = __builtin_nontemporal_load(&atom[e]);
  int rank = atomicAdd(&count[a], 1);
  unsigned u = (__float_as_uint(r) & 0xFFFFFF00u) | (unsigned)(rank & 0xFF);
  r_all[e] = __uint_as_float(u);
}

// coalesced scan, pass A: per-block (1024-wide) sums
__global__ __launch_bounds__(1024) void bsum_kernel(const int* __restrict__ count,
                                                    int* __restrict__ bsum, int n) {
  __shared__ int red[1024];
  int t = threadIdx.x;
  int i = blockIdx.x * 1024 + t;
  red[t] = (i < n) ? count[i] : 0;
  __syncthreads();
  for (int d = 512; d > 0; d >>= 1) {
    if (t < d) red[t] += red[t + d];
    __syncthreads();
  }
  if (t == 0) bsum[blockIdx.x] = red[0];
}

// pass B: exclusive scan of block sums (nb <= 1024), in LDS
__global__ __launch_bounds__(1024) void bscan_kernel(const int* __restrict__ bsum,
                                                     int* __restrict__ bbase, int nb) {
  __shared__ int v[1024];
  int t = threadIdx.x;
  v[t] = (t < nb) ? bsum[t] : 0;
  __syncthreads();
  if (t == 0) {
    int run = 0;
    for (int i = 0; i < nb; ++i) { int c = v[i]; v[i] = run; run += c; }
  }
  __syncthreads();
  if (t < nb) bbase[t] = v[t];
}

// pass C: in-block Hillis-Steele scan + block base; coalesced offset write
__global__ __launch_bounds__(1024) void apply_kernel(const int* __restrict__ count,
                                                     const int* __restrict__ bbase,
                                                     int* __restrict__ offset, int n) {
  __shared__ int part[1024];
  int t = threadIdx.x;
  int i = blockIdx.x * 1024 + t;
  int x = (i < n) ? count[i] : 0;
  part[t] = x;
  __syncthreads();
  for (int d = 1; d < 1024; d <<= 1) {
    int add = (t >= d) ? part[t - d] : 0;
    __syncthreads();
    part[t] += add;
    __syncthreads();
  }
  int excl = part[t] - x + bbase[blockIdx.x];
  if (i < n) offset[i] = excl;
}

// Rank-based scatter (R20 win): ZERO atomics, single pass.
__global__ __launch_bounds__(256) void scatter_rank_kernel(
    const float* __restrict__ r_all, const int* __restrict__ atom,
    const int* __restrict__ offset, float* __restrict__ sr, int E) {
  int e = blockIdx.x * blockDim.x + threadIdx.x;
  if (e >= E) return;
  unsigned u = __float_as_uint(__builtin_nontemporal_load(&r_all[e]));
  int a = __builtin_nontemporal_load(&atom[e]);
  int dst = offset[a] + (int)(u & 0xFFu);
  sr[dst] = __uint_as_float(u);
}

// R22: fused build+gram, F KEPT for proj (R15's regression was dropping F
// and recomputing powers in proj; the fusion itself was never isolated).
// Per atom: register accumulation of 32 powers -> coalesced F write ->
// padded-LDS staging -> per-block 528-pair f64 Gram reduction -> atomics.
// Saves gram's 12.8MB F re-read + one launch.
__global__ __launch_bounds__(256) void buildgram_kernel(const float* __restrict__ sr,
                                                        const int* __restrict__ offset,
                                                        const int* __restrict__ count,
                                                        float* __restrict__ F,
                                                        double* __restrict__ G,
                                                        double* __restrict__ S, int n) {
  __shared__ float rows[256][MAX_K + 1];  // +1 pad: conflict-free
  int tid = threadIdx.x;
  int a = blockIdx.x * 256 + tid;
  float acc[MAX_K];
#pragma unroll
  for (int k = 0; k < MAX_K; ++k) acc[k] = 0.f;
  if (a < n) {
    int o = offset[a], c = count[a];
    for (int i = 0; i < c; ++i) {
      float r = sr[o + i];
      float p = 1.f;
#pragma unroll
      for (int k = 0; k < MAX_K; ++k) { acc[k] += p; p *= r; }
    }
    float4* out = (float4*)(F + (size_t)a * MAX_K);
#pragma unroll
    for (int k4 = 0; k4 < 8; ++k4)
      out[k4] = make_float4(acc[4 * k4], acc[4 * k4 + 1], acc[4 * k4 + 2], acc[4 * k4 + 3]);
  }
#pragma unroll
  for (int k = 0; k < MAX_K; ++k) rows[tid][k] = acc[k];
  __syncthreads();

  int pi[3], pj[3];
  int npair = 0;
  for (int p = tid; p < 528; p += 256) {
    int i = 0, pp = p;
    while (pp >= MAX_K - i) { pp -= (MAX_K - i); i++; }
    pi[npair] = i;
    pj[npair] = i + pp;
    npair++;
  }
  double accp[3] = {0.0, 0.0, 0.0};
  double colsum = 0.0;
  for (int r = 0; r < 256; ++r) {
    for (int t = 0; t < npair; ++t)
      accp[t] += (double)rows[r][pi[t]] * (double)rows[r][pj[t]];
    if (tid < MAX_K) colsum += (double)rows[r][tid];
  }
  for (int t = 0; t < npair; ++t) atomicAdd(&G[pi[t] * MAX_K + pj[t]], accp[t]);
  if (tid < MAX_K) atomicAdd(&S[tid], colsum);
}

// ---------------- fallback path (small ws): direct atomics ----------------
__global__ __launch_bounds__(256) void edge_kernel(const float* __restrict__ vec,
                                                   const int* __restrict__ atom,
                                                   float* __restrict__ F, int E) {
  int e = blockIdx.x * blockDim.x + threadIdx.x;
  if (e >= E) return;
  float x = vec[3 * e + 0], y = vec[3 * e + 1], z = vec[3 * e + 2];
  float r = sqrtf(x * x + y * y + z * z) * (1.0f / CUTOFF);
  float* out = F + (size_t)atom[e] * MAX_K;
  float p = 1.0f;
#pragma unroll
  for (int k = 0; k < MAX_K; ++k) {
    atomicAdd(out + k, p);
    p *= r;
  }
}

// fallback gram (reads F)
__global__ __launch_bounds__(256) void gram_kernel(const float* __restrict__ F, int n,
                                                   double* __restrict__ G,
                                                   double* __restrict__ S) {
  __shared__ float rows[8][MAX_K];
  int tid = threadIdx.x;
  int pi[3], pj[3];
  int npair = 0;
  for (int p = tid; p < 528; p += 256) {
    int i = 0, pp = p;
    while (pp >= MAX_K - i) { pp -= (MAX_K - i); i++; }
    pi[npair] = i;
    pj[npair] = i + pp;
    npair++;
  }
  double acc[3] = {0.0, 0.0, 0.0};
  double colsum = 0.0;
  int nchunk = (n + 7) / 8;
  int row = tid >> 5, col = tid & 31;
  for (int ch = blockIdx.x; ch < nchunk; ch += gridDim.x) {
    int a = ch * 8 + row;
    rows[row][col] = (a < n) ? F[(size_t)a * MAX_K + col] : 0.0f;
    __syncthreads();
#pragma unroll
    for (int r = 0; r < 8; ++r) {
      for (int t = 0; t < npair; ++t)
        acc[t] += (double)rows[r][pi[t]] * (double)rows[r][pj[t]];
      if (tid < MAX_K) colsum += (double)rows[r][tid];
    }
    __syncthreads();
  }
  for (int t = 0; t < npair; ++t) atomicAdd(&G[pi[t] * MAX_K + pj[t]], acc[t]);
  if (tid < MAX_K) atomicAdd(&S[tid], colsum);
}

// Pass 3 (1 block = 4 waves, 256 thr): centered Gram, parallel Jacobi,
// 2x2-block update, fully f32 iteration (R21 win; error model verified
// absmax 1.0 << 4.96). Centering f64 before the cast.
__global__ __launch_bounds__(256) void eig_kernel(const double* __restrict__ Gin,
                                                  const double* __restrict__ S,
                                                  float* __restrict__ V3, int n_atoms) {
  __shared__ float A[32][33];
  __shared__ float V[32][33];
  __shared__ float rcs[16], rss[16];
  __shared__ double wred[4];
  __shared__ int sel[3];
  __shared__ double ssign[3];
  int t = threadIdx.x;
  int ki = t >> 4;   // row-pair slot
  int kj = t & 15;   // col-pair slot

  double stot = 0.0;
  for (int k = 0; k < 32; ++k) stot += S[k];
  double mu = stot / ((double)n_atoms * 32.0);

  for (int idx = t; idx < 1024; idx += 256) {
    int i = idx >> 5, j = idx & 31;
    double g = (i <= j) ? Gin[i * 32 + j] : Gin[j * 32 + i];
    A[i][j] = (float)(g - mu * (S[i] + S[j]) + mu * mu * (double)n_atoms);
    V[i][j] = (i == j) ? 1.0f : 0.0f;
  }
  __syncthreads();

  double part = 0.0;
  for (int idx = t; idx < 1024; idx += 256) {
    int i = idx >> 5, j = idx & 31;
    part += (double)A[i][j] * (double)A[i][j];
  }
  for (int o = 32; o; o >>= 1) part += __shfl_xor(part, o, 64);
  if ((t & 63) == 0) wred[t >> 6] = part;
  __syncthreads();
  double fro2 = wred[0] + wred[1] + wred[2] + wred[3];
  float fro_f = (float)sqrt(fro2);
  float skip_thr = 1e-7f * fro_f;
  double off_tol2 = fro2 * 1e-12;
  __syncthreads();

  int q0 = 0;
  int ai_ = ki, bi_ = (ki == 0) ? 0 : (31 - ki);
  int aj_ = kj, bj_ = (kj == 0) ? 0 : (31 - kj);
  int ma = (t < 16) ? t : 0;
  int mb = (t >= 1 && t < 16) ? (31 - t) : 0;

  for (int sweep = 0; sweep < 8; ++sweep) {
    double off = 0.0;
    for (int idx = t; idx < 1024; idx += 256) {
      int i = idx >> 5, j = idx & 31;
      if (i != j) off += (double)A[i][j] * (double)A[i][j];
    }
    for (int o = 32; o; o >>= 1) off += __shfl_xor(off, o, 64);
    if ((t & 63) == 0) wred[t >> 6] = off;
    __syncthreads();
    double offT = wred[0] + wred[1] + wred[2] + wred[3];
    __syncthreads();
    if (offT <= off_tol2) break;

    for (int r = 0; r < 31; ++r) {
      if (t < 16) {
        float cf = 1.0f, sf = 0.0f;
        int p, q;
        if (t == 0) { p = 31; q = q0; }
        else { p = (ma < mb) ? ma : mb; q = (ma < mb) ? mb : ma; }
        float apq = A[p][q];
        if (fabsf(apq) > skip_thr) {
          float app = A[p][p], aqq = A[q][q];
          float tau = (aqq - app) / (2.0f * apq);
          float tt = 1.0f / (fabsf(tau) + sqrtf(1.0f + tau * tau));
          if (tau < 0.0f) tt = -tt;
          cf = 1.0f / sqrtf(1.0f + tt * tt);
          sf = tt * cf;
        }
        rcs[t] = cf; rss[t] = sf;
      }
      __syncthreads();  // B1

      int pi_, qi_, pj_, qj_;
      if (ki == 0) { pi_ = 31; qi_ = q0; }
      else { pi_ = (ai_ < bi_) ? ai_ : bi_; qi_ = (ai_ < bi_) ? bi_ : ai_; }
      if (kj == 0) { pj_ = 31; qj_ = q0; }
      else { pj_ = (aj_ < bj_) ? aj_ : bj_; qj_ = (aj_ < bj_) ? bj_ : aj_; }
      float ci = rcs[ki], si = rss[ki];
      float cj = rcs[kj], sj = rss[kj];
      float m00 = A[pi_][pj_], m01 = A[pi_][qj_];
      float m10 = A[qi_][pj_], m11 = A[qi_][qj_];
      float r00 = ci * m00 - si * m10, r01 = ci * m01 - si * m11;
      float r10 = si * m00 + ci * m10, r11 = si * m01 + ci * m11;
      A[pi_][pj_] = cj * r00 - sj * r01;
      A[pi_][qj_] = sj * r00 + cj * r01;
      A[qi_][pj_] = cj * r10 - sj * r11;
      A[qi_][qj_] = sj * r10 + cj * r11;
      float v00 = V[pi_][pj_], v01 = V[pi_][qj_];
      float v10 = V[qi_][pj_], v11 = V[qi_][qj_];
      V[pi_][pj_] = cj * v00 - sj * v01;
      V[pi_][qj_] = sj * v00 + cj * v01;
      V[qi_][pj_] = cj * v10 - sj * v11;
      V[qi_][qj_] = sj * v10 + cj * v11;
      __syncthreads();  // B2

      ai_ = (ai_ == 30) ? 0 : ai_ + 1;
      bi_ = (bi_ == 30) ? 0 : bi_ + 1;
      aj_ = (aj_ == 30) ? 0 : aj_ + 1;
      bj_ = (bj_ == 30) ? 0 : bj_ + 1;
      ma = (ma == 30) ? 0 : ma + 1;
      mb = (mb == 30) ? 0 : mb + 1;
      q0 = (q0 == 30) ? 0 : q0 + 1;
    }
  }
  __syncthreads();

  if (t == 0) {
    bool used[32];
    for (int i = 0; i < 32; ++i) used[i] = false;
    for (int j = 0; j < 3; ++j) {
      int best = 0; float bv = -1e30f;
      for (int i = 0; i < 32; ++i)
        if (!used[i] && A[i][i] > bv) { bv = A[i][i]; best = i; }
      used[best] = true;
      sel[j] = best;
      int m = 0; float mv = fabsf(V[0][best]);
      for (int i = 1; i < 32; ++i) {
        float av = fabsf(V[i][best]);
        if (av > mv) { mv = av; m = i; }
      }
      ssign[j] = (V[m][best] < 0.0f) ? -1.0 : 1.0;
    }
  }
  __syncthreads();
  const float adj[3] = {SIGN0, SIGN1, SIGN2};
  if (t < 32) {
    for (int j = 0; j < 3; ++j)
      V3[j * 32 + t] = (float)ssign[j] * V[t][sel[j]] * adj[j];
  }
}

// Pass 4: out[a, j] = sum_k F[a,k] * V3[j,k]
__global__ __launch_bounds__(256) void proj_kernel(const float* __restrict__ F,
                                                   const float* __restrict__ V3,
                                                   float* __restrict__ out, int n) {
  __shared__ float v[96];
  if (threadIdx.x < 96) v[threadIdx.x] = V3[threadIdx.x];
  __syncthreads();
  int a = blockIdx.x * blockDim.x + threadIdx.x;
  if (a >= n) return;
  const float4* rowp = (const float4*)(F + (size_t)a * 32);
  float s0 = 0.f, s1 = 0.f, s2 = 0.f;
#pragma unroll
  for (int k4 = 0; k4 < 8; ++k4) {
    float4 f = rowp[k4];
    int k = k4 * 4;
    s0 += f.x * v[k] + f.y * v[k + 1] + f.z * v[k + 2] + f.w * v[k + 3];
    s1 += f.x * v[32 + k] + f.y * v[32 + k + 1] + f.z * v[32 + k + 2] + f.w * v[32 + k + 3];
    s2 += f.x * v[64 + k] + f.y * v[64 + k + 1] + f.z * v[64 + k + 2] + f.w * v[64 + k + 3];
  }
  out[3 * a + 0] = s0;
  out[3 * a + 1] = s1;
  out[3 * a + 2] = s2;
}

extern "C" void kernel_launch(void* const* d_in, const int* in_sizes, int n_in,
                              void* d_out, int out_size, void* d_ws, size_t ws_size,
                              hipStream_t stream) {
  const float* vec = (const float*)d_in[0];
  const int* atom = (const int*)d_in[1];
  int E = in_sizes[1];
  int n_atoms = out_size / 3;
  int nb = (n_atoms + 1023) >> 10;  // blocks for the coalesced scan (<=1024)

  char* ws = (char*)d_ws;
  auto nalign = [](size_t x) { return (x + 255) & ~(size_t)255; };

  size_t F_bytes = (size_t)n_atoms * MAX_K * sizeof(float);
  size_t sr_bytes = (size_t)E * sizeof(float);
  size_t i_bytes = (size_t)n_atoms * sizeof(int);

  size_t F_off = 0;
  size_t sr_off = nalign(F_off + F_bytes);
  size_t offs_off = nalign(sr_off + sr_bytes);
  size_t cur_off = nalign(offs_off + i_bytes);   // kept in layout (unused now)
  size_t cnt_off = nalign(cur_off + i_bytes);
  size_t G_off = nalign(cnt_off + i_bytes);
  size_t S_off = nalign(G_off + 1024 * sizeof(double));
  size_t bs_off = nalign(S_off + 32 * sizeof(double));
  size_t bb_off = nalign(bs_off + 1024 * sizeof(int));
  size_t V3_off = nalign(bb_off + 1024 * sizeof(int));
  size_t total = nalign(V3_off + 96 * sizeof(float));

  float* F = (float*)(ws + F_off);
  double* G = (double*)(ws + G_off);
  double* S = (double*)(ws + S_off);
  float* V3 = (float*)(ws + V3_off);

  // r_all aliases F's buffer (E*4B == n_atoms*32*4B); F written only by
  // buildgram_kernel, after the scatter has fully consumed r_all.
  float* r_all = F;

  if (ws_size >= total && sr_bytes <= F_bytes) {
    float* sr = (float*)(ws + sr_off);
    int* offset = (int*)(ws + offs_off);
    int* count = (int*)(ws + cnt_off);
    int* bsum = (int*)(ws + bs_off);
    int* bbase = (int*)(ws + bb_off);
    // zero count + G + S (contiguous region)
    hipMemsetAsync(ws + cnt_off, 0, S_off + 32 * sizeof(double) - cnt_off, stream);
    r_hist_kernel<<<(E + 255) / 256, 256, 0, stream>>>(vec, atom, r_all, count, E);
    bsum_kernel<<<nb, 1024, 0, stream>>>(count, bsum, n_atoms);
    bscan_kernel<<<1, 1024, 0, stream>>>(bsum, bbase, nb);
    apply_kernel<<<nb, 1024, 0, stream>>>(count, bbase, offset, n_atoms);
    scatter_rank_kernel<<<(E + 255) / 256, 256, 0, stream>>>(r_all, atom, offset, sr, E);
    buildgram_kernel<<<(n_atoms + 255) / 256, 256, 0, stream>>>(sr, offset, count, F, G, S, n_atoms);
    eig_kernel<<<1, 256, 0, stream>>>(G, S, V3, n_atoms);
    proj_kernel<<<(n_atoms + 255) / 256, 256, 0, stream>>>(F, V3, (float*)d_out, n_atoms);
  } else {
    hipMemsetAsync(ws, 0, F_bytes, stream);
    hipMemsetAsync(ws + cnt_off, 0, S_off + 32 * sizeof(double) - cnt_off, stream);
    edge_kernel<<<(E + 255) / 256, 256, 0, stream>>>(vec, atom, F, E);
    gram_kernel<<<1024, 256, 0, stream>>>(F, n_atoms, G, S);
    eig_kernel<<<1, 256, 0, stream>>>(G, S, V3, n_atoms);
    proj_kernel<<<(n_atoms + 255) / 256, 256, 0, stream>>>(F, V3, (float*)d_out, n_atoms);
  }
}

// Round 23
// 417.722 us; speedup vs baseline: 1.0553x; 1.0553x over previous
//
#include <hip/hip_runtime.h>
#include <math.h>

#define MAX_K 32
#define CUTOFF 5.0f

// Sign map (resolved R1-R6): canonical(max-component-positive) -> LAPACK.
#define SIGN0 -1.0f
#define SIGN1 -1.0f
#define SIGN2 -1.0f

// ---------------- fast path: counting-sort by atom ----------------
// R22 lesson: buildgram fusion regressed (-55us): fused gram lost grid
// parallelism (391 deep blocks vs 1024 shallow). F re-read is cheap
// streaming; keep build and gram separate (R21 structure).

// fused: per-edge r + RANK TAGGING (R20 win). One memory-side atomic per
// edge (~23 G/s floor, R6/R21 measured); WRITE_SIZE ~112MB = 3.2M x 32B
// RMW is intrinsic. All streams nt (use-once).
__global__ __launch_bounds__(256) void r_hist_kernel(const float* __restrict__ vec,
                                                     const int* __restrict__ atom,
                                                     float* __restrict__ r_all,
                                                     int* __restrict__ count, int E) {
  int e = blockIdx.x * blockDim.x + threadIdx.x;
  if (e >= E) return;
  float x = __builtin_nontemporal_load(&vec[3 * e + 0]);
  float y = __builtin_nontemporal_load(&vec[3 * e + 1]);
  float z = __builtin_nontemporal_load(&vec[3 * e + 2]);
  float r = sqrtf(x * x + y * y + z * z) * (1.0f / CUTOFF);
  int a = __builtin_nontemporal_load(&atom[e]);
  int rank = atomicAdd(&count[a], 1);
  unsigned u = (__float_as_uint(r) & 0xFFFFFF00u) | (unsigned)(rank & 0xFF);
  r_all[e] = __uint_as_float(u);
}

// coalesced scan, pass A: per-block (1024-wide) sums
__global__ __launch_bounds__(1024) void bsum_kernel(const int* __restrict__ count,
                                                    int* __restrict__ bsum, int n) {
  __shared__ int red[1024];
  int t = threadIdx.x;
  int i = blockIdx.x * 1024 + t;
  red[t] = (i < n) ? count[i] : 0;
  __syncthreads();
  for (int d = 512; d > 0; d >>= 1) {
    if (t < d) red[t] += red[t + d];
    __syncthreads();
  }
  if (t == 0) bsum[blockIdx.x] = red[0];
}

// pass B: exclusive scan of block sums (nb <= 1024), in LDS
__global__ __launch_bounds__(1024) void bscan_kernel(const int* __restrict__ bsum,
                                                     int* __restrict__ bbase, int nb) {
  __shared__ int v[1024];
  int t = threadIdx.x;
  v[t] = (t < nb) ? bsum[t] : 0;
  __syncthreads();
  if (t == 0) {
    int run = 0;
    for (int i = 0; i < nb; ++i) { int c = v[i]; v[i] = run; run += c; }
  }
  __syncthreads();
  if (t < nb) bbase[t] = v[t];
}

// pass C: in-block Hillis-Steele scan + block base; coalesced offset write
__global__ __launch_bounds__(1024) void apply_kernel(const int* __restrict__ count,
                                                     const int* __restrict__ bbase,
                                                     int* __restrict__ offset, int n) {
  __shared__ int part[1024];
  int t = threadIdx.x;
  int i = blockIdx.x * 1024 + t;
  int x = (i < n) ? count[i] : 0;
  part[t] = x;
  __syncthreads();
  for (int d = 1; d < 1024; d <<= 1) {
    int add = (t >= d) ? part[t - d] : 0;
    __syncthreads();
    part[t] += add;
    __syncthreads();
  }
  int excl = part[t] - x + bbase[blockIdx.x];
  if (i < n) offset[i] = excl;
}

// Rank-based scatter (R20 win): ZERO atomics, single pass.
__global__ __launch_bounds__(256) void scatter_rank_kernel(
    const float* __restrict__ r_all, const int* __restrict__ atom,
    const int* __restrict__ offset, float* __restrict__ sr, int E) {
  int e = blockIdx.x * blockDim.x + threadIdx.x;
  if (e >= E) return;
  unsigned u = __float_as_uint(__builtin_nontemporal_load(&r_all[e]));
  int a = __builtin_nontemporal_load(&atom[e]);
  int dst = offset[a] + (int)(u & 0xFFu);
  sr[dst] = __uint_as_float(u);
}

// build: per-atom register accumulation of all 32 powers; coalesced F write.
__global__ __launch_bounds__(256) void build_kernel(const float* __restrict__ sr,
                                                    const int* __restrict__ offset,
                                                    const int* __restrict__ count,
                                                    float* __restrict__ F, int n) {
  int a = blockIdx.x * blockDim.x + threadIdx.x;
  if (a >= n) return;
  float acc[MAX_K];
#pragma unroll
  for (int k = 0; k < MAX_K; ++k) acc[k] = 0.f;
  int o = offset[a], c = count[a];
  for (int i = 0; i < c; ++i) {
    float r = sr[o + i];
    float p = 1.f;
#pragma unroll
    for (int k = 0; k < MAX_K; ++k) { acc[k] += p; p *= r; }
  }
  float4* out = (float4*)(F + (size_t)a * MAX_K);
#pragma unroll
  for (int k4 = 0; k4 < 8; ++k4)
    out[k4] = make_float4(acc[4 * k4], acc[4 * k4 + 1], acc[4 * k4 + 2], acc[4 * k4 + 3]);
}

// ---------------- fallback path (small ws): direct atomics ----------------
__global__ __launch_bounds__(256) void edge_kernel(const float* __restrict__ vec,
                                                   const int* __restrict__ atom,
                                                   float* __restrict__ F, int E) {
  int e = blockIdx.x * blockDim.x + threadIdx.x;
  if (e >= E) return;
  float x = vec[3 * e + 0], y = vec[3 * e + 1], z = vec[3 * e + 2];
  float r = sqrtf(x * x + y * y + z * z) * (1.0f / CUTOFF);
  float* out = F + (size_t)atom[e] * MAX_K;
  float p = 1.0f;
#pragma unroll
  for (int k = 0; k < MAX_K; ++k) {
    atomicAdd(out + k, p);
    p *= r;
  }
}

// Pass 2: G = F^T F (upper triangle) and column sums S, accumulated in f64.
__global__ __launch_bounds__(256) void gram_kernel(const float* __restrict__ F, int n,
                                                   double* __restrict__ G,
                                                   double* __restrict__ S) {
  __shared__ float rows[8][MAX_K];
  int tid = threadIdx.x;
  int pi[3], pj[3];
  int npair = 0;
  for (int p = tid; p < 528; p += 256) {
    int i = 0, pp = p;
    while (pp >= MAX_K - i) { pp -= (MAX_K - i); i++; }
    pi[npair] = i;
    pj[npair] = i + pp;
    npair++;
  }
  double acc[3] = {0.0, 0.0, 0.0};
  double colsum = 0.0;
  int nchunk = (n + 7) / 8;
  int row = tid >> 5, col = tid & 31;
  for (int ch = blockIdx.x; ch < nchunk; ch += gridDim.x) {
    int a = ch * 8 + row;
    rows[row][col] = (a < n) ? F[(size_t)a * MAX_K + col] : 0.0f;
    __syncthreads();
#pragma unroll
    for (int r = 0; r < 8; ++r) {
      for (int t = 0; t < npair; ++t)
        acc[t] += (double)rows[r][pi[t]] * (double)rows[r][pj[t]];
      if (tid < MAX_K) colsum += (double)rows[r][tid];
    }
    __syncthreads();
  }
  for (int t = 0; t < npair; ++t) atomicAdd(&G[pi[t] * MAX_K + pj[t]], acc[t]);
  if (tid < MAX_K) atomicAdd(&S[tid], colsum);
}

// Pass 3 (1 block = 4 waves, 256 thr): centered Gram, parallel Jacobi,
// 2x2-block update, fully f32 iteration (R21 win; absmax 1.0 << 4.96).
__global__ __launch_bounds__(256) void eig_kernel(const double* __restrict__ Gin,
                                                  const double* __restrict__ S,
                                                  float* __restrict__ V3, int n_atoms) {
  __shared__ float A[32][33];
  __shared__ float V[32][33];
  __shared__ float rcs[16], rss[16];
  __shared__ double wred[4];
  __shared__ int sel[3];
  __shared__ double ssign[3];
  int t = threadIdx.x;
  int ki = t >> 4;   // row-pair slot
  int kj = t & 15;   // col-pair slot

  double stot = 0.0;
  for (int k = 0; k < 32; ++k) stot += S[k];
  double mu = stot / ((double)n_atoms * 32.0);

  for (int idx = t; idx < 1024; idx += 256) {
    int i = idx >> 5, j = idx & 31;
    double g = (i <= j) ? Gin[i * 32 + j] : Gin[j * 32 + i];
    A[i][j] = (float)(g - mu * (S[i] + S[j]) + mu * mu * (double)n_atoms);
    V[i][j] = (i == j) ? 1.0f : 0.0f;
  }
  __syncthreads();

  double part = 0.0;
  for (int idx = t; idx < 1024; idx += 256) {
    int i = idx >> 5, j = idx & 31;
    part += (double)A[i][j] * (double)A[i][j];
  }
  for (int o = 32; o; o >>= 1) part += __shfl_xor(part, o, 64);
  if ((t & 63) == 0) wred[t >> 6] = part;
  __syncthreads();
  double fro2 = wred[0] + wred[1] + wred[2] + wred[3];
  float fro_f = (float)sqrt(fro2);
  float skip_thr = 1e-7f * fro_f;
  double off_tol2 = fro2 * 1e-12;
  __syncthreads();

  int q0 = 0;
  int ai_ = ki, bi_ = (ki == 0) ? 0 : (31 - ki);
  int aj_ = kj, bj_ = (kj == 0) ? 0 : (31 - kj);
  int ma = (t < 16) ? t : 0;
  int mb = (t >= 1 && t < 16) ? (31 - t) : 0;

  for (int sweep = 0; sweep < 8; ++sweep) {
    double off = 0.0;
    for (int idx = t; idx < 1024; idx += 256) {
      int i = idx >> 5, j = idx & 31;
      if (i != j) off += (double)A[i][j] * (double)A[i][j];
    }
    for (int o = 32; o; o >>= 1) off += __shfl_xor(off, o, 64);
    if ((t & 63) == 0) wred[t >> 6] = off;
    __syncthreads();
    double offT = wred[0] + wred[1] + wred[2] + wred[3];
    __syncthreads();
    if (offT <= off_tol2) break;

    for (int r = 0; r < 31; ++r) {
      if (t < 16) {
        float cf = 1.0f, sf = 0.0f;
        int p, q;
        if (t == 0) { p = 31; q = q0; }
        else { p = (ma < mb) ? ma : mb; q = (ma < mb) ? mb : ma; }
        float apq = A[p][q];
        if (fabsf(apq) > skip_thr) {
          float app = A[p][p], aqq = A[q][q];
          float tau = (aqq - app) / (2.0f * apq);
          float tt = 1.0f / (fabsf(tau) + sqrtf(1.0f + tau * tau));
          if (tau < 0.0f) tt = -tt;
          cf = 1.0f / sqrtf(1.0f + tt * tt);
          sf = tt * cf;
        }
        rcs[t] = cf; rss[t] = sf;
      }
      __syncthreads();  // B1

      int pi_, qi_, pj_, qj_;
      if (ki == 0) { pi_ = 31; qi_ = q0; }
      else { pi_ = (ai_ < bi_) ? ai_ : bi_; qi_ = (ai_ < bi_) ? bi_ : ai_; }
      if (kj == 0) { pj_ = 31; qj_ = q0; }
      else { pj_ = (aj_ < bj_) ? aj_ : bj_; qj_ = (aj_ < bj_) ? bj_ : aj_; }
      float ci = rcs[ki], si = rss[ki];
      float cj = rcs[kj], sj = rss[kj];
      float m00 = A[pi_][pj_], m01 = A[pi_][qj_];
      float m10 = A[qi_][pj_], m11 = A[qi_][qj_];
      float r00 = ci * m00 - si * m10, r01 = ci * m01 - si * m11;
      float r10 = si * m00 + ci * m10, r11 = si * m01 + ci * m11;
      A[pi_][pj_] = cj * r00 - sj * r01;
      A[pi_][qj_] = sj * r00 + cj * r01;
      A[qi_][pj_] = cj * r10 - sj * r11;
      A[qi_][qj_] = sj * r10 + cj * r11;
      float v00 = V[pi_][pj_], v01 = V[pi_][qj_];
      float v10 = V[qi_][pj_], v11 = V[qi_][qj_];
      V[pi_][pj_] = cj * v00 - sj * v01;
      V[pi_][qj_] = sj * v00 + cj * v01;
      V[qi_][pj_] = cj * v10 - sj * v11;
      V[qi_][qj_] = sj * v10 + cj * v11;
      __syncthreads();  // B2

      ai_ = (ai_ == 30) ? 0 : ai_ + 1;
      bi_ = (bi_ == 30) ? 0 : bi_ + 1;
      aj_ = (aj_ == 30) ? 0 : aj_ + 1;
      bj_ = (bj_ == 30) ? 0 : bj_ + 1;
      ma = (ma == 30) ? 0 : ma + 1;
      mb = (mb == 30) ? 0 : mb + 1;
      q0 = (q0 == 30) ? 0 : q0 + 1;
    }
  }
  __syncthreads();

  if (t == 0) {
    bool used[32];
    for (int i = 0; i < 32; ++i) used[i] = false;
    for (int j = 0; j < 3; ++j) {
      int best = 0; float bv = -1e30f;
      for (int i = 0; i < 32; ++i)
        if (!used[i] && A[i][i] > bv) { bv = A[i][i]; best = i; }
      used[best] = true;
      sel[j] = best;
      int m = 0; float mv = fabsf(V[0][best]);
      for (int i = 1; i < 32; ++i) {
        float av = fabsf(V[i][best]);
        if (av > mv) { mv = av; m = i; }
      }
      ssign[j] = (V[m][best] < 0.0f) ? -1.0 : 1.0;
    }
  }
  __syncthreads();
  const float adj[3] = {SIGN0, SIGN1, SIGN2};
  if (t < 32) {
    for (int j = 0; j < 3; ++j)
      V3[j * 32 + t] = (float)ssign[j] * V[t][sel[j]] * adj[j];
  }
}

// Pass 4: out[a, j] = sum_k F[a,k] * V3[j,k]
__global__ __launch_bounds__(256) void proj_kernel(const float* __restrict__ F,
                                                   const float* __restrict__ V3,
                                                   float* __restrict__ out, int n) {
  __shared__ float v[96];
  if (threadIdx.x < 96) v[threadIdx.x] = V3[threadIdx.x];
  __syncthreads();
  int a = blockIdx.x * blockDim.x + threadIdx.x;
  if (a >= n) return;
  const float4* rowp = (const float4*)(F + (size_t)a * 32);
  float s0 = 0.f, s1 = 0.f, s2 = 0.f;
#pragma unroll
  for (int k4 = 0; k4 < 8; ++k4) {
    float4 f = rowp[k4];
    int k = k4 * 4;
    s0 += f.x * v[k] + f.y * v[k + 1] + f.z * v[k + 2] + f.w * v[k + 3];
    s1 += f.x * v[32 + k] + f.y * v[32 + k + 1] + f.z * v[32 + k + 2] + f.w * v[32 + k + 3];
    s2 += f.x * v[64 + k] + f.y * v[64 + k + 1] + f.z * v[64 + k + 2] + f.w * v[64 + k + 3];
  }
  out[3 * a + 0] = s0;
  out[3 * a + 1] = s1;
  out[3 * a + 2] = s2;
}

extern "C" void kernel_launch(void* const* d_in, const int* in_sizes, int n_in,
                              void* d_out, int out_size, void* d_ws, size_t ws_size,
                              hipStream_t stream) {
  const float* vec = (const float*)d_in[0];
  const int* atom = (const int*)d_in[1];
  int E = in_sizes[1];
  int n_atoms = out_size / 3;
  int nb = (n_atoms + 1023) >> 10;  // blocks for the coalesced scan (<=1024)

  char* ws = (char*)d_ws;
  auto nalign = [](size_t x) { return (x + 255) & ~(size_t)255; };

  size_t F_bytes = (size_t)n_atoms * MAX_K * sizeof(float);
  size_t sr_bytes = (size_t)E * sizeof(float);
  size_t i_bytes = (size_t)n_atoms * sizeof(int);

  size_t F_off = 0;
  size_t sr_off = nalign(F_off + F_bytes);
  size_t offs_off = nalign(sr_off + sr_bytes);
  size_t cur_off = nalign(offs_off + i_bytes);   // kept in layout (unused now)
  size_t cnt_off = nalign(cur_off + i_bytes);
  size_t G_off = nalign(cnt_off + i_bytes);
  size_t S_off = nalign(G_off + 1024 * sizeof(double));
  size_t bs_off = nalign(S_off + 32 * sizeof(double));
  size_t bb_off = nalign(bs_off + 1024 * sizeof(int));
  size_t V3_off = nalign(bb_off + 1024 * sizeof(int));
  size_t total = nalign(V3_off + 96 * sizeof(float));

  float* F = (float*)(ws + F_off);
  double* G = (double*)(ws + G_off);
  double* S = (double*)(ws + S_off);
  float* V3 = (float*)(ws + V3_off);

  // r_all aliases F's buffer (E*4B == n_atoms*32*4B); F written only by
  // build_kernel, after the scatter has fully consumed r_all.
  float* r_all = F;

  if (ws_size >= total && sr_bytes <= F_bytes) {
    float* sr = (float*)(ws + sr_off);
    int* offset = (int*)(ws + offs_off);
    int* count = (int*)(ws + cnt_off);
    int* bsum = (int*)(ws + bs_off);
    int* bbase = (int*)(ws + bb_off);
    // zero count + G + S (contiguous region)
    hipMemsetAsync(ws + cnt_off, 0, S_off + 32 * sizeof(double) - cnt_off, stream);
    r_hist_kernel<<<(E + 255) / 256, 256, 0, stream>>>(vec, atom, r_all, count, E);
    bsum_kernel<<<nb, 1024, 0, stream>>>(count, bsum, n_atoms);
    bscan_kernel<<<1, 1024, 0, stream>>>(bsum, bbase, nb);
    apply_kernel<<<nb, 1024, 0, stream>>>(count, bbase, offset, n_atoms);
    scatter_rank_kernel<<<(E + 255) / 256, 256, 0, stream>>>(r_all, atom, offset, sr, E);
    build_kernel<<<(n_atoms + 255) / 256, 256, 0, stream>>>(sr, offset, count, F, n_atoms);
    gram_kernel<<<1024, 256, 0, stream>>>(F, n_atoms, G, S);
    eig_kernel<<<1, 256, 0, stream>>>(G, S, V3, n_atoms);
    proj_kernel<<<(n_atoms + 255) / 256, 256, 0, stream>>>(F, V3, (float*)d_out, n_atoms);
  } else {
    hipMemsetAsync(ws, 0, F_bytes, stream);
    hipMemsetAsync(ws + cnt_off, 0, S_off + 32 * sizeof(double) - cnt_off, stream);
    edge_kernel<<<(E + 255) / 256, 256, 0, stream>>>(vec, atom, F, E);
    gram_kernel<<<1024, 256, 0, stream>>>(F, n_atoms, G, S);
    eig_kernel<<<1, 256, 0, stream>>>(G, S, V3, n_atoms);
    proj_kernel<<<(n_atoms + 255) / 256, 256, 0, stream>>>(F, V3, (float*)d_out, n_atoms);
  }
}

// Round 24
// 386.317 us; speedup vs baseline: 1.1410x; 1.0813x over previous
//
#include <hip/hip_runtime.h>
#include <math.h>

#define MAX_K 32
#define CUTOFF 5.0f

// Sign map (resolved R1-R6): canonical(max-component-positive) -> LAPACK.
#define SIGN0 -1.0f
#define SIGN1 -1.0f
#define SIGN2 -1.0f

// ---------------- fast path: counting-sort by atom ----------------
// R22: buildgram fusion regressed (fused gram lost grid parallelism) ->
// keep build/gram separate. R23: nt on the atom load regressed (atom is
// re-read by scatter next kernel; caching it in L2/L3 helps, nt evicted
// it) -> nt ONLY on vec (truly use-once).

// fused: per-edge r + RANK TAGGING (R20 win). One memory-side atomic per
// edge (~23 G/s floor, R6/R21 measured); WRITE_SIZE ~112MB = 3.2M x 32B
// RMW is intrinsic.
__global__ __launch_bounds__(256) void r_hist_kernel(const float* __restrict__ vec,
                                                     const int* __restrict__ atom,
                                                     float* __restrict__ r_all,
                                                     int* __restrict__ count, int E) {
  int e = blockIdx.x * blockDim.x + threadIdx.x;
  if (e >= E) return;
  float x = __builtin_nontemporal_load(&vec[3 * e + 0]);
  float y = __builtin_nontemporal_load(&vec[3 * e + 1]);
  float z = __builtin_nontemporal_load(&vec[3 * e + 2]);
  float r = sqrtf(x * x + y * y + z * z) * (1.0f / CUTOFF);
  int rank = atomicAdd(&count[atom[e]], 1);
  unsigned u = (__float_as_uint(r) & 0xFFFFFF00u) | (unsigned)(rank & 0xFF);
  r_all[e] = __uint_as_float(u);
}

// coalesced scan, pass A: per-block (1024-wide) sums
__global__ __launch_bounds__(1024) void bsum_kernel(const int* __restrict__ count,
                                                    int* __restrict__ bsum, int n) {
  __shared__ int red[1024];
  int t = threadIdx.x;
  int i = blockIdx.x * 1024 + t;
  red[t] = (i < n) ? count[i] : 0;
  __syncthreads();
  for (int d = 512; d > 0; d >>= 1) {
    if (t < d) red[t] += red[t + d];
    __syncthreads();
  }
  if (t == 0) bsum[blockIdx.x] = red[0];
}

// pass B: exclusive scan of block sums (nb <= 1024), in LDS
__global__ __launch_bounds__(1024) void bscan_kernel(const int* __restrict__ bsum,
                                                     int* __restrict__ bbase, int nb) {
  __shared__ int v[1024];
  int t = threadIdx.x;
  v[t] = (t < nb) ? bsum[t] : 0;
  __syncthreads();
  if (t == 0) {
    int run = 0;
    for (int i = 0; i < nb; ++i) { int c = v[i]; v[i] = run; run += c; }
  }
  __syncthreads();
  if (t < nb) bbase[t] = v[t];
}

// pass C: in-block Hillis-Steele scan + block base; coalesced offset write
__global__ __launch_bounds__(1024) void apply_kernel(const int* __restrict__ count,
                                                     const int* __restrict__ bbase,
                                                     int* __restrict__ offset, int n) {
  __shared__ int part[1024];
  int t = threadIdx.x;
  int i = blockIdx.x * 1024 + t;
  int x = (i < n) ? count[i] : 0;
  part[t] = x;
  __syncthreads();
  for (int d = 1; d < 1024; d <<= 1) {
    int add = (t >= d) ? part[t - d] : 0;
    __syncthreads();
    part[t] += add;
    __syncthreads();
  }
  int excl = part[t] - x + bbase[blockIdx.x];
  if (i < n) offset[i] = excl;
}

// Rank-based scatter (R20 win): ZERO atomics, single pass.
__global__ __launch_bounds__(256) void scatter_rank_kernel(
    const float* __restrict__ r_all, const int* __restrict__ atom,
    const int* __restrict__ offset, float* __restrict__ sr, int E) {
  int e = blockIdx.x * blockDim.x + threadIdx.x;
  if (e >= E) return;
  unsigned u = __float_as_uint(__builtin_nontemporal_load(&r_all[e]));
  int a = __builtin_nontemporal_load(&atom[e]);
  int dst = offset[a] + (int)(u & 0xFFu);
  sr[dst] = __uint_as_float(u);
}

// build: per-atom register accumulation of all 32 powers; coalesced F write.
__global__ __launch_bounds__(256) void build_kernel(const float* __restrict__ sr,
                                                    const int* __restrict__ offset,
                                                    const int* __restrict__ count,
                                                    float* __restrict__ F, int n) {
  int a = blockIdx.x * blockDim.x + threadIdx.x;
  if (a >= n) return;
  float acc[MAX_K];
#pragma unroll
  for (int k = 0; k < MAX_K; ++k) acc[k] = 0.f;
  int o = offset[a], c = count[a];
  for (int i = 0; i < c; ++i) {
    float r = sr[o + i];
    float p = 1.f;
#pragma unroll
    for (int k = 0; k < MAX_K; ++k) { acc[k] += p; p *= r; }
  }
  float4* out = (float4*)(F + (size_t)a * MAX_K);
#pragma unroll
  for (int k4 = 0; k4 < 8; ++k4)
    out[k4] = make_float4(acc[4 * k4], acc[4 * k4 + 1], acc[4 * k4 + 2], acc[4 * k4 + 3]);
}

// ---------------- fallback path (small ws): direct atomics ----------------
__global__ __launch_bounds__(256) void edge_kernel(const float* __restrict__ vec,
                                                   const int* __restrict__ atom,
                                                   float* __restrict__ F, int E) {
  int e = blockIdx.x * blockDim.x + threadIdx.x;
  if (e >= E) return;
  float x = vec[3 * e + 0], y = vec[3 * e + 1], z = vec[3 * e + 2];
  float r = sqrtf(x * x + y * y + z * z) * (1.0f / CUTOFF);
  float* out = F + (size_t)atom[e] * MAX_K;
  float p = 1.0f;
#pragma unroll
  for (int k = 0; k < MAX_K; ++k) {
    atomicAdd(out + k, p);
    p *= r;
  }
}

// Pass 2: G = F^T F (upper triangle) and column sums S, accumulated in f64.
__global__ __launch_bounds__(256) void gram_kernel(const float* __restrict__ F, int n,
                                                   double* __restrict__ G,
                                                   double* __restrict__ S) {
  __shared__ float rows[8][MAX_K];
  int tid = threadIdx.x;
  int pi[3], pj[3];
  int npair = 0;
  for (int p = tid; p < 528; p += 256) {
    int i = 0, pp = p;
    while (pp >= MAX_K - i) { pp -= (MAX_K - i); i++; }
    pi[npair] = i;
    pj[npair] = i + pp;
    npair++;
  }
  double acc[3] = {0.0, 0.0, 0.0};
  double colsum = 0.0;
  int nchunk = (n + 7) / 8;
  int row = tid >> 5, col = tid & 31;
  for (int ch = blockIdx.x; ch < nchunk; ch += gridDim.x) {
    int a = ch * 8 + row;
    rows[row][col] = (a < n) ? F[(size_t)a * MAX_K + col] : 0.0f;
    __syncthreads();
#pragma unroll
    for (int r = 0; r < 8; ++r) {
      for (int t = 0; t < npair; ++t)
        acc[t] += (double)rows[r][pi[t]] * (double)rows[r][pj[t]];
      if (tid < MAX_K) colsum += (double)rows[r][tid];
    }
    __syncthreads();
  }
  for (int t = 0; t < npair; ++t) atomicAdd(&G[pi[t] * MAX_K + pj[t]], acc[t]);
  if (tid < MAX_K) atomicAdd(&S[tid], colsum);
}

// Pass 3 (1 block = 4 waves, 256 thr): centered Gram, parallel Jacobi,
// 2x2-block update, fully f32 iteration (R21 win; absmax 1.0 << 4.96).
__global__ __launch_bounds__(256) void eig_kernel(const double* __restrict__ Gin,
                                                  const double* __restrict__ S,
                                                  float* __restrict__ V3, int n_atoms) {
  __shared__ float A[32][33];
  __shared__ float V[32][33];
  __shared__ float rcs[16], rss[16];
  __shared__ double wred[4];
  __shared__ int sel[3];
  __shared__ double ssign[3];
  int t = threadIdx.x;
  int ki = t >> 4;   // row-pair slot
  int kj = t & 15;   // col-pair slot

  double stot = 0.0;
  for (int k = 0; k < 32; ++k) stot += S[k];
  double mu = stot / ((double)n_atoms * 32.0);

  for (int idx = t; idx < 1024; idx += 256) {
    int i = idx >> 5, j = idx & 31;
    double g = (i <= j) ? Gin[i * 32 + j] : Gin[j * 32 + i];
    A[i][j] = (float)(g - mu * (S[i] + S[j]) + mu * mu * (double)n_atoms);
    V[i][j] = (i == j) ? 1.0f : 0.0f;
  }
  __syncthreads();

  double part = 0.0;
  for (int idx = t; idx < 1024; idx += 256) {
    int i = idx >> 5, j = idx & 31;
    part += (double)A[i][j] * (double)A[i][j];
  }
  for (int o = 32; o; o >>= 1) part += __shfl_xor(part, o, 64);
  if ((t & 63) == 0) wred[t >> 6] = part;
  __syncthreads();
  double fro2 = wred[0] + wred[1] + wred[2] + wred[3];
  float fro_f = (float)sqrt(fro2);
  float skip_thr = 1e-7f * fro_f;
  double off_tol2 = fro2 * 1e-12;
  __syncthreads();

  int q0 = 0;
  int ai_ = ki, bi_ = (ki == 0) ? 0 : (31 - ki);
  int aj_ = kj, bj_ = (kj == 0) ? 0 : (31 - kj);
  int ma = (t < 16) ? t : 0;
  int mb = (t >= 1 && t < 16) ? (31 - t) : 0;

  for (int sweep = 0; sweep < 8; ++sweep) {
    double off = 0.0;
    for (int idx = t; idx < 1024; idx += 256) {
      int i = idx >> 5, j = idx & 31;
      if (i != j) off += (double)A[i][j] * (double)A[i][j];
    }
    for (int o = 32; o; o >>= 1) off += __shfl_xor(off, o, 64);
    if ((t & 63) == 0) wred[t >> 6] = off;
    __syncthreads();
    double offT = wred[0] + wred[1] + wred[2] + wred[3];
    __syncthreads();
    if (offT <= off_tol2) break;

    for (int r = 0; r < 31; ++r) {
      if (t < 16) {
        float cf = 1.0f, sf = 0.0f;
        int p, q;
        if (t == 0) { p = 31; q = q0; }
        else { p = (ma < mb) ? ma : mb; q = (ma < mb) ? mb : ma; }
        float apq = A[p][q];
        if (fabsf(apq) > skip_thr) {
          float app = A[p][p], aqq = A[q][q];
          float tau = (aqq - app) / (2.0f * apq);
          float tt = 1.0f / (fabsf(tau) + sqrtf(1.0f + tau * tau));
          if (tau < 0.0f) tt = -tt;
          cf = 1.0f / sqrtf(1.0f + tt * tt);
          sf = tt * cf;
        }
        rcs[t] = cf; rss[t] = sf;
      }
      __syncthreads();  // B1

      int pi_, qi_, pj_, qj_;
      if (ki == 0) { pi_ = 31; qi_ = q0; }
      else { pi_ = (ai_ < bi_) ? ai_ : bi_; qi_ = (ai_ < bi_) ? bi_ : ai_; }
      if (kj == 0) { pj_ = 31; qj_ = q0; }
      else { pj_ = (aj_ < bj_) ? aj_ : bj_; qj_ = (aj_ < bj_) ? bj_ : aj_; }
      float ci = rcs[ki], si = rss[ki];
      float cj = rcs[kj], sj = rss[kj];
      float m00 = A[pi_][pj_], m01 = A[pi_][qj_];
      float m10 = A[qi_][pj_], m11 = A[qi_][qj_];
      float r00 = ci * m00 - si * m10, r01 = ci * m01 - si * m11;
      float r10 = si * m00 + ci * m10, r11 = si * m01 + ci * m11;
      A[pi_][pj_] = cj * r00 - sj * r01;
      A[pi_][qj_] = sj * r00 + cj * r01;
      A[qi_][pj_] = cj * r10 - sj * r11;
      A[qi_][qj_] = sj * r10 + cj * r11;
      float v00 = V[pi_][pj_], v01 = V[pi_][qj_];
      float v10 = V[qi_][pj_], v11 = V[qi_][qj_];
      V[pi_][pj_] = cj * v00 - sj * v01;
      V[pi_][qj_] = sj * v00 + cj * v01;
      V[qi_][pj_] = cj * v10 - sj * v11;
      V[qi_][qj_] = sj * v10 + cj * v11;
      __syncthreads();  // B2

      ai_ = (ai_ == 30) ? 0 : ai_ + 1;
      bi_ = (bi_ == 30) ? 0 : bi_ + 1;
      aj_ = (aj_ == 30) ? 0 : aj_ + 1;
      bj_ = (bj_ == 30) ? 0 : bj_ + 1;
      ma = (ma == 30) ? 0 : ma + 1;
      mb = (mb == 30) ? 0 : mb + 1;
      q0 = (q0 == 30) ? 0 : q0 + 1;
    }
  }
  __syncthreads();

  if (t == 0) {
    bool used[32];
    for (int i = 0; i < 32; ++i) used[i] = false;
    for (int j = 0; j < 3; ++j) {
      int best = 0; float bv = -1e30f;
      for (int i = 0; i < 32; ++i)
        if (!used[i] && A[i][i] > bv) { bv = A[i][i]; best = i; }
      used[best] = true;
      sel[j] = best;
      int m = 0; float mv = fabsf(V[0][best]);
      for (int i = 1; i < 32; ++i) {
        float av = fabsf(V[i][best]);
        if (av > mv) { mv = av; m = i; }
      }
      ssign[j] = (V[m][best] < 0.0f) ? -1.0 : 1.0;
    }
  }
  __syncthreads();
  const float adj[3] = {SIGN0, SIGN1, SIGN2};
  if (t < 32) {
    for (int j = 0; j < 3; ++j)
      V3[j * 32 + t] = (float)ssign[j] * V[t][sel[j]] * adj[j];
  }
}

// Pass 4: out[a, j] = sum_k F[a,k] * V3[j,k]
__global__ __launch_bounds__(256) void proj_kernel(const float* __restrict__ F,
                                                   const float* __restrict__ V3,
                                                   float* __restrict__ out, int n) {
  __shared__ float v[96];
  if (threadIdx.x < 96) v[threadIdx.x] = V3[threadIdx.x];
  __syncthreads();
  int a = blockIdx.x * blockDim.x + threadIdx.x;
  if (a >= n) return;
  const float4* rowp = (const float4*)(F + (size_t)a * 32);
  float s0 = 0.f, s1 = 0.f, s2 = 0.f;
#pragma unroll
  for (int k4 = 0; k4 < 8; ++k4) {
    float4 f = rowp[k4];
    int k = k4 * 4;
    s0 += f.x * v[k] + f.y * v[k + 1] + f.z * v[k + 2] + f.w * v[k + 3];
    s1 += f.x * v[32 + k] + f.y * v[32 + k + 1] + f.z * v[32 + k + 2] + f.w * v[32 + k + 3];
    s2 += f.x * v[64 + k] + f.y * v[64 + k + 1] + f.z * v[64 + k + 2] + f.w * v[64 + k + 3];
  }
  out[3 * a + 0] = s0;
  out[3 * a + 1] = s1;
  out[3 * a + 2] = s2;
}

extern "C" void kernel_launch(void* const* d_in, const int* in_sizes, int n_in,
                              void* d_out, int out_size, void* d_ws, size_t ws_size,
                              hipStream_t stream) {
  const float* vec = (const float*)d_in[0];
  const int* atom = (const int*)d_in[1];
  int E = in_sizes[1];
  int n_atoms = out_size / 3;
  int nb = (n_atoms + 1023) >> 10;  // blocks for the coalesced scan (<=1024)

  char* ws = (char*)d_ws;
  auto nalign = [](size_t x) { return (x + 255) & ~(size_t)255; };

  size_t F_bytes = (size_t)n_atoms * MAX_K * sizeof(float);
  size_t sr_bytes = (size_t)E * sizeof(float);
  size_t i_bytes = (size_t)n_atoms * sizeof(int);

  size_t F_off = 0;
  size_t sr_off = nalign(F_off + F_bytes);
  size_t offs_off = nalign(sr_off + sr_bytes);
  size_t cur_off = nalign(offs_off + i_bytes);   // kept in layout (unused now)
  size_t cnt_off = nalign(cur_off + i_bytes);
  size_t G_off = nalign(cnt_off + i_bytes);
  size_t S_off = nalign(G_off + 1024 * sizeof(double));
  size_t bs_off = nalign(S_off + 32 * sizeof(double));
  size_t bb_off = nalign(bs_off + 1024 * sizeof(int));
  size_t V3_off = nalign(bb_off + 1024 * sizeof(int));
  size_t total = nalign(V3_off + 96 * sizeof(float));

  float* F = (float*)(ws + F_off);
  double* G = (double*)(ws + G_off);
  double* S = (double*)(ws + S_off);
  float* V3 = (float*)(ws + V3_off);

  // r_all aliases F's buffer (E*4B == n_atoms*32*4B); F written only by
  // build_kernel, after the scatter has fully consumed r_all.
  float* r_all = F;

  if (ws_size >= total && sr_bytes <= F_bytes) {
    float* sr = (float*)(ws + sr_off);
    int* offset = (int*)(ws + offs_off);
    int* count = (int*)(ws + cnt_off);
    int* bsum = (int*)(ws + bs_off);
    int* bbase = (int*)(ws + bb_off);
    // zero count + G + S (contiguous region)
    hipMemsetAsync(ws + cnt_off, 0, S_off + 32 * sizeof(double) - cnt_off, stream);
    r_hist_kernel<<<(E + 255) / 256, 256, 0, stream>>>(vec, atom, r_all, count, E);
    bsum_kernel<<<nb, 1024, 0, stream>>>(count, bsum, n_atoms);
    bscan_kernel<<<1, 1024, 0, stream>>>(bsum, bbase, nb);
    apply_kernel<<<nb, 1024, 0, stream>>>(count, bbase, offset, n_atoms);
    scatter_rank_kernel<<<(E + 255) / 256, 256, 0, stream>>>(r_all, atom, offset, sr, E);
    build_kernel<<<(n_atoms + 255) / 256, 256, 0, stream>>>(sr, offset, count, F, n_atoms);
    gram_kernel<<<1024, 256, 0, stream>>>(F, n_atoms, G, S);
    eig_kernel<<<1, 256, 0, stream>>>(G, S, V3, n_atoms);
    proj_kernel<<<(n_atoms + 255) / 256, 256, 0, stream>>>(F, V3, (float*)d_out, n_atoms);
  } else {
    hipMemsetAsync(ws, 0, F_bytes, stream);
    hipMemsetAsync(ws + cnt_off, 0, S_off + 32 * sizeof(double) - cnt_off, stream);
    edge_kernel<<<(E + 255) / 256, 256, 0, stream>>>(vec, atom, F, E);
    gram_kernel<<<1024, 256, 0, stream>>>(F, n_atoms, G, S);
    eig_kernel<<<1, 256, 0, stream>>>(G, S, V3, n_atoms);
    proj_kernel<<<(n_atoms + 255) / 256, 256, 0, stream>>>(F, V3, (float*)d_out, n_atoms);
  }
}